// Round 3
// baseline (522.605 us; speedup 1.0000x reference)
//
#include <hip/hip_runtime.h>
#include <hip/hip_bf16.h>

#define BN_EPS 1e-5f

typedef short bf16x8 __attribute__((ext_vector_type(8)));
typedef float f32x4 __attribute__((ext_vector_type(4)));

static __device__ __forceinline__ unsigned short f2bf(float f) {
    unsigned u = __float_as_uint(f);
    unsigned r = (u + 0x7FFF + ((u >> 16) & 1)) >> 16;
    return (unsigned short)r;
}
static __device__ __forceinline__ float bf2f(unsigned short s) {
    return __uint_as_float((unsigned)s << 16);
}
__device__ __forceinline__ int pad4i(int c) { return (c + 3) & ~3; }

#define BIN_SHIFT 9
#define BIN_NODES 512
#define P1_CHUNK 8192
#define P1_THREADS 1024
#define P1_PER_THREAD (P1_CHUNK / P1_THREADS)   // 8
#define IMG_CAP 12288
#define P2_THREADS 512

// ---------------- phase 1: partition edges into fixed-capacity 512-node bins
// Each bin b owns ebuf[b*ecap .. (b+1)*ecap). bincur[b] is the running fill
// cursor (zeroed by memset). 1024 threads/block (16 waves) for latency hiding;
// dst values cached in registers across the two passes.
__global__ __launch_bounds__(P1_THREADS) void phase1_kernel(
        const int* __restrict__ src, const int* __restrict__ dst,
        int* __restrict__ bincur, int* __restrict__ ebuf, int e, int ecap) {
    __shared__ int hist[256], base[256], cur[256];
    int t = threadIdx.x;
    int c0 = blockIdx.x * P1_CHUNK;
    int iend = c0 + P1_CHUNK; if (iend > e) iend = e;
    if (t < 256) hist[t] = 0;
    __syncthreads();
    int dreg[P1_PER_THREAD];
#pragma unroll
    for (int u = 0; u < P1_PER_THREAD; u++) {
        int i = c0 + t + u * P1_THREADS;
        if (i < iend) {
            int d = dst[i];
            dreg[u] = d;
            atomicAdd(&hist[d >> BIN_SHIFT], 1);
        }
    }
    __syncthreads();
    if (t < 256) {
        if (hist[t] > 0)
            base[t] = t * ecap + atomicAdd(&bincur[t], hist[t]);
        cur[t] = 0;
    }
    __syncthreads();
#pragma unroll
    for (int u = 0; u < P1_PER_THREAD; u++) {
        int i = c0 + t + u * P1_THREADS;
        if (i < iend) {
            int s = src[i], d = dreg[u];
            int b = d >> BIN_SHIFT;
            int r = atomicAdd(&cur[b], 1);
            int p = base[b] + r;
            if (p < (b + 1) * ecap)                 // capacity guard (never in practice)
                ebuf[p] = s | ((d & (BIN_NODES - 1)) << 17);
        }
    }
}

// ---------------- per-node counts + dinv + row_start/row_len ---------------
// Bin CSR bases allocated via one global atomicAdd (bins need not be ordered),
// eliminating the separate scan kernel and its full-device drain.
// Also zeroes the sentinel row of h_a (fused). 1024 threads (16 waves).
__global__ __launch_bounds__(1024) void bincount_kernel(
        const int* __restrict__ ebuf, const int* __restrict__ bincur, int ecap,
        float* __restrict__ dinv, int* __restrict__ row_start,
        int* __restrict__ row_len, int* __restrict__ binbase,
        int* __restrict__ binpad, int* __restrict__ gtotal,
        unsigned short* __restrict__ ha_sent, int n) {
    __shared__ int c512[BIN_NODES];
    __shared__ int sd[256];
    __shared__ int rbs;
    int b = blockIdx.x, t = threadIdx.x;
    if (b == 0 && t < 64) ha_sent[t] = 0;           // zero sentinel row (fused)
    if (t < BIN_NODES) c512[t] = 0;
    __syncthreads();
    int cnt_b = bincur[b]; if (cnt_b > ecap) cnt_b = ecap;
    int e0 = b * ecap, e1 = e0 + cnt_b;
    for (int j = e0 + t; j < e1; j += 1024)
        atomicAdd(&c512[ebuf[j] >> 17], 1);
    __syncthreads();
    int n0 = b * BIN_NODES;
    // dinv (counts +1 for self-loop)
    if (t < BIN_NODES) {
        int i = n0 + t;
        if (i < n) dinv[i] = rsqrtf((float)(c512[t] + 1));
    }
    // exclusive prefix scan of pad4(count) over 512 nodes (2 per lead thread)
    int v0 = 0, v1 = 0, tsum = 0;
    if (t < 256) {
        v0 = pad4i(c512[2 * t]);
        v1 = pad4i(c512[2 * t + 1]);
        tsum = v0 + v1;
        sd[t] = tsum;
    }
    __syncthreads();
    for (int off = 1; off < 256; off <<= 1) {
        int x = 0;
        if (t < 256 && t >= off) x = sd[t - off];
        __syncthreads();
        if (t < 256) sd[t] += x;
        __syncthreads();
    }
    if (t == 0) {
        int tot = sd[255];
        int rb = atomicAdd(gtotal, tot);
        rbs = rb; binbase[b] = rb; binpad[b] = tot;
    }
    __syncthreads();
    if (t < 256) {
        int rb = rbs;
        int excl = sd[t] - tsum;
        int i0 = n0 + 2 * t, i1 = i0 + 1;
        if (i0 < n) { row_start[i0] = rb + excl;      row_len[i0] = v0; }
        if (i1 < n) { row_start[i1] = rb + excl + v0; row_len[i1] = v1; }
    }
}

// ---------------- phase 2: per-bin CSR build in LDS, coalesced write-out ----
__global__ __launch_bounds__(P2_THREADS) void phase2_kernel(
        const int* __restrict__ ebuf, const int* __restrict__ bincur, int ecap,
        const int* __restrict__ row_start, const int* __restrict__ row_len,
        const int* __restrict__ binbase, const int* __restrict__ binpad,
        int* __restrict__ csr, int* __restrict__ gcursor, int n, int sentinel) {
    __shared__ int image[IMG_CAP];
    __shared__ int lcur[BIN_NODES];
    __shared__ int rl[BIN_NODES];
    int b = blockIdx.x, t = threadIdx.x;
    int n0 = b * BIN_NODES;
    int nloc = n - n0; if (nloc > BIN_NODES) nloc = BIN_NODES;
    int rb = binbase[b];
    int rspan = binpad[b];
    int cnt_b = bincur[b]; if (cnt_b > ecap) cnt_b = ecap;
    int e0 = b * ecap, e1 = e0 + cnt_b;
    if (t < BIN_NODES) {
        rl[t] = (t < nloc) ? row_start[n0 + t] - rb : 0;
        lcur[t] = 0;
    }
    __syncthreads();
    if (rspan <= IMG_CAP) {
        for (int k = t; k < rspan; k += P2_THREADS) image[k] = sentinel;
        __syncthreads();
        for (int j = e0 + t; j < e1; j += P2_THREADS) {
            int en = ebuf[j];
            int s = en & 0x1FFFF;
            int dl = en >> 17;
            int pos = rl[dl] + atomicAdd(&lcur[dl], 1);
            image[pos] = s;
        }
        __syncthreads();
        for (int k = t; k < rspan; k += P2_THREADS) csr[rb + k] = image[k];
    } else {                                        // statistically never
        for (int k = t; k < nloc; k += P2_THREADS) gcursor[n0 + k] = 0;
        __syncthreads();
        for (int j = e0 + t; j < e1; j += P2_THREADS) {
            int en = ebuf[j];
            int s = en & 0x1FFFF;
            int dl = en >> 17;
            int pos = rb + rl[dl] + atomicAdd(&gcursor[n0 + dl], 1);
            csr[pos] = s;
        }
        __syncthreads();
        for (int k = t; k < nloc; k += P2_THREADS) { // fill pads with sentinel
            int node = n0 + k;
            int st = rb + rl[k] + gcursor[node];
            int en2 = rb + rl[k] + row_len[node];
            for (int pos = st; pos < en2; pos++) csr[pos] = sentinel;
        }
    }
}

// ---------------- MFMA linear: hs[N,64] = dinv[r] * (in[N,K] @ w[K,64]) ----
template<int K, bool BF16IN>
__global__ __launch_bounds__(256) void lin_mfma(const void* __restrict__ in_,
                                                const float* __restrict__ w,
                                                const float* __restrict__ dinv,
                                                unsigned short* __restrict__ outbf, int n) {
    constexpr int XS = K + 8;
    __shared__ unsigned short xs[64 * XS];
    __shared__ unsigned short wt[64 * XS];
    int t = threadIdx.x;
    int row0 = blockIdx.x * 64;
    int nrows = n - row0; if (nrows > 64) nrows = 64;

    {
        const float4* w4 = (const float4*)w;
        for (int idx = t; idx < K * 16; idx += 256) {
            int k = idx >> 4, c4 = (idx & 15) * 4;
            float4 v = w4[idx];
            wt[(c4 + 0) * XS + k] = f2bf(v.x);
            wt[(c4 + 1) * XS + k] = f2bf(v.y);
            wt[(c4 + 2) * XS + k] = f2bf(v.z);
            wt[(c4 + 3) * XS + k] = f2bf(v.w);
        }
    }
    if constexpr (BF16IN) {
        const uint4* in4 = (const uint4*)((const unsigned short*)in_ + (size_t)row0 * K);
        int total8 = nrows * (K / 8);
        for (int idx = t; idx < total8; idx += 256) {
            int r = idx / (K / 8), kk = idx - r * (K / 8);
            uint4 v = in4[idx];
            *(uint4*)&xs[r * XS + kk * 8] = v;
        }
    } else {
        const float4* in4 = (const float4*)((const float*)in_ + (size_t)row0 * K);
        int total4 = nrows * (K / 4);
        for (int idx = t; idx < total4; idx += 256) {
            int r = idx / (K / 4), kk = idx - r * (K / 4);
            float4 v = in4[idx];
            ushort4 s4;
            s4.x = f2bf(v.x); s4.y = f2bf(v.y); s4.z = f2bf(v.z); s4.w = f2bf(v.w);
            *(ushort4*)&xs[r * XS + kk * 4] = s4;
        }
    }
    __syncthreads();

    int lane = t & 63;
    int wid = t >> 6;
    int quad = lane >> 4;
    int l15 = lane & 15;

    f32x4 acc[4];
#pragma unroll
    for (int cg_ = 0; cg_ < 4; cg_++) acc[cg_] = (f32x4){0.f, 0.f, 0.f, 0.f};

    const unsigned short* xrow = &xs[(wid * 16 + l15) * XS + quad * 8];
#pragma unroll
    for (int kc = 0; kc < K / 32; kc++) {
        bf16x8 bfrag = *(const bf16x8*)(xrow + kc * 32);
#pragma unroll
        for (int cg_ = 0; cg_ < 4; cg_++) {
            bf16x8 afrag = *(const bf16x8*)&wt[(cg_ * 16 + l15) * XS + kc * 32 + quad * 8];
            acc[cg_] = __builtin_amdgcn_mfma_f32_16x16x32_bf16(afrag, bfrag, acc[cg_], 0, 0, 0);
        }
    }

    int grow = row0 + wid * 16 + l15;
    if (grow < n) {
        float dv = dinv[grow];
#pragma unroll
        for (int cg_ = 0; cg_ < 4; cg_++) {
            ushort4 st;
            st.x = f2bf(acc[cg_][0] * dv);
            st.y = f2bf(acc[cg_][1] * dv);
            st.z = f2bf(acc[cg_][2] * dv);
            st.w = f2bf(acc[cg_][3] * dv);
            *(ushort4*)&outbf[(size_t)grow * 64 + cg_ * 16 + quad * 4] = st;
        }
    }
}

// ---------------- aggregation + bias + BN + ReLU (quarter-wave gathers) ----
// Wave = 1 node. 4 quarters of 16 lanes; quarter q handles edge j+q, each
// lane loading dwordx2 (4 bf16 features) of that edge's source row -> one
// gather instruction fetches 4 rows (512 B). Rows are pad-4 so the 4-edge
// step is exact. 2-stage shfl_xor butterfly combines quarters at the end.
// POOL: fuse global_add_pool of the output (layer 2 only).
template<bool POOL>
__global__ __launch_bounds__(256) void agg_kernel(
        const unsigned short* __restrict__ hs, const int* __restrict__ row_start,
        const int* __restrict__ row_len, const int* __restrict__ csr,
        const float* __restrict__ dinv,
        const float* __restrict__ bias, const float* __restrict__ gam,
        const float* __restrict__ bet, const float* __restrict__ mu,
        const float* __restrict__ var,
        unsigned short* __restrict__ out,
        const int* __restrict__ batch, float* __restrict__ pooled, int n) {
    int iw = blockIdx.x * 4 + (threadIdx.x >> 6);
    int lane = threadIdx.x & 63;
    if (iw >= n) return;                            // wave-uniform exit
    int i = __builtin_amdgcn_readfirstlane(iw);
    int q = lane >> 4;                              // edge slot within 4-group
    int m = lane & 15;                              // feature quad index
    const unsigned short* hb = hs + (size_t)m * 4;  // lane's feature base
    float a0 = 0.f, a1 = 0.f, a2 = 0.f, a3 = 0.f;
    if (q == 0) {                                   // self-loop, quarter 0 only
        uint2 v = *(const uint2*)(hb + ((size_t)(unsigned)i << 6));
        a0 += __uint_as_float(v.x << 16);
        a1 += __uint_as_float(v.x & 0xFFFF0000u);
        a2 += __uint_as_float(v.y << 16);
        a3 += __uint_as_float(v.y & 0xFFFF0000u);
    }
    int rs = __builtin_amdgcn_readfirstlane(row_start[i]);
    int re = rs + __builtin_amdgcn_readfirstlane(row_len[i]);   // x4 padded
    int j = rs;
    for (; j + 16 <= re; j += 16) {
        int s0 = csr[j + q];
        int s1 = csr[j + 4 + q];
        int s2 = csr[j + 8 + q];
        int s3 = csr[j + 12 + q];
        uint2 v0 = *(const uint2*)(hb + ((size_t)(unsigned)s0 << 6));
        uint2 v1 = *(const uint2*)(hb + ((size_t)(unsigned)s1 << 6));
        uint2 v2 = *(const uint2*)(hb + ((size_t)(unsigned)s2 << 6));
        uint2 v3 = *(const uint2*)(hb + ((size_t)(unsigned)s3 << 6));
        a0 += __uint_as_float(v0.x << 16);          a1 += __uint_as_float(v0.x & 0xFFFF0000u);
        a2 += __uint_as_float(v0.y << 16);          a3 += __uint_as_float(v0.y & 0xFFFF0000u);
        a0 += __uint_as_float(v1.x << 16);          a1 += __uint_as_float(v1.x & 0xFFFF0000u);
        a2 += __uint_as_float(v1.y << 16);          a3 += __uint_as_float(v1.y & 0xFFFF0000u);
        a0 += __uint_as_float(v2.x << 16);          a1 += __uint_as_float(v2.x & 0xFFFF0000u);
        a2 += __uint_as_float(v2.y << 16);          a3 += __uint_as_float(v2.y & 0xFFFF0000u);
        a0 += __uint_as_float(v3.x << 16);          a1 += __uint_as_float(v3.x & 0xFFFF0000u);
        a2 += __uint_as_float(v3.y << 16);          a3 += __uint_as_float(v3.y & 0xFFFF0000u);
    }
    for (; j < re; j += 4) {
        int s0 = csr[j + q];
        uint2 v0 = *(const uint2*)(hb + ((size_t)(unsigned)s0 << 6));
        a0 += __uint_as_float(v0.x << 16);          a1 += __uint_as_float(v0.x & 0xFFFF0000u);
        a2 += __uint_as_float(v0.y << 16);          a3 += __uint_as_float(v0.y & 0xFFFF0000u);
    }
    // combine quarters (butterfly): all lanes end with full feature sums
    a0 += __shfl_xor(a0, 16); a1 += __shfl_xor(a1, 16);
    a2 += __shfl_xor(a2, 16); a3 += __shfl_xor(a3, 16);
    a0 += __shfl_xor(a0, 32); a1 += __shfl_xor(a1, 32);
    a2 += __shfl_xor(a2, 32); a3 += __shfl_xor(a3, 32);
    float dv = dinv[i];
    if (q == 0) {                                   // lanes 0-15 write 8B each
        float4 bs4 = *(const float4*)&bias[4 * m];
        float4 gm4 = *(const float4*)&gam[4 * m];
        float4 bt4 = *(const float4*)&bet[4 * m];
        float4 mu4 = *(const float4*)&mu[4 * m];
        float4 vr4 = *(const float4*)&var[4 * m];
        float r0 = (a0 * dv + bs4.x - mu4.x) * (gm4.x * rsqrtf(vr4.x + BN_EPS)) + bt4.x;
        float r1 = (a1 * dv + bs4.y - mu4.y) * (gm4.y * rsqrtf(vr4.y + BN_EPS)) + bt4.y;
        float r2 = (a2 * dv + bs4.z - mu4.z) * (gm4.z * rsqrtf(vr4.z + BN_EPS)) + bt4.z;
        float r3 = (a3 * dv + bs4.w - mu4.w) * (gm4.w * rsqrtf(vr4.w + BN_EPS)) + bt4.w;
        ushort4 st;
        st.x = f2bf(r0 > 0.f ? r0 : 0.f);
        st.y = f2bf(r1 > 0.f ? r1 : 0.f);
        st.z = f2bf(r2 > 0.f ? r2 : 0.f);
        st.w = f2bf(r3 > 0.f ? r3 : 0.f);
        *(ushort4*)&out[((size_t)(unsigned)i << 6) + 4 * m] = st;
        if (POOL) {
            int g = __builtin_amdgcn_readfirstlane(batch[i]);
            float* pp = &pooled[(size_t)g * 64 + 4 * m];
            atomicAdd(pp + 0, bf2f(st.x));          // bf16-rounded, matching
            atomicAdd(pp + 1, bf2f(st.y));          // the old separate pool
            atomicAdd(pp + 2, bf2f(st.z));
            atomicAdd(pp + 3, bf2f(st.w));
        }
    }
}

// ---------------- pool stage 2: tiny MLP per graph ----------------
__global__ void mlp_kernel(const float* __restrict__ pooled,
                           const float* __restrict__ l1w, const float* __restrict__ l1b,
                           const float* __restrict__ l2w, const float* __restrict__ l2b,
                           float* __restrict__ out) {
    int g = blockIdx.x;
    int lane = threadIdx.x;
    __shared__ float p[64];
    __shared__ float h1[32];
    p[lane] = pooled[(size_t)g * 64 + lane];
    __syncthreads();
    if (lane < 32) {
        float a = l1b[lane];
#pragma unroll 8
        for (int k = 0; k < 64; k++) a += p[k] * l1w[k * 32 + lane];
        h1[lane] = a > 0.f ? a : 0.f;
    }
    __syncthreads();
    if (lane < 2) {
        float a = l2b[lane];
#pragma unroll 8
        for (int j = 0; j < 32; j++) a += h1[j] * l2w[j * 2 + lane];
        out[g * 2 + lane] = a;
    }
}

extern "C" void kernel_launch(void* const* d_in, const int* in_sizes, int n_in,
                              void* d_out, int out_size, void* d_ws, size_t ws_size,
                              hipStream_t stream) {
    const float* x     = (const float*)d_in[0];
    const int*   ei    = (const int*)d_in[1];
    const int*   batch = (const int*)d_in[2];
    const float* w0 = (const float*)d_in[3];
    const float* b0 = (const float*)d_in[4];
    const float* w1 = (const float*)d_in[5];
    const float* b1 = (const float*)d_in[6];
    const float* w2 = (const float*)d_in[7];
    const float* b2 = (const float*)d_in[8];
    const float* g0 = (const float*)d_in[9];
    const float* be0 = (const float*)d_in[10];
    const float* m0 = (const float*)d_in[11];
    const float* v0 = (const float*)d_in[12];
    const float* g1 = (const float*)d_in[13];
    const float* be1 = (const float*)d_in[14];
    const float* m1 = (const float*)d_in[15];
    const float* v1 = (const float*)d_in[16];
    const float* g2 = (const float*)d_in[17];
    const float* be2 = (const float*)d_in[18];
    const float* m2 = (const float*)d_in[19];
    const float* v2 = (const float*)d_in[20];
    const float* l1w = (const float*)d_in[21];
    const float* l1b = (const float*)d_in[22];
    const float* l2w = (const float*)d_in[23];
    const float* l2b = (const float*)d_in[24];
    float* out = (float*)d_out;

    const int N = in_sizes[2];
    const int E = in_sizes[1] / 2;
    const int G = out_size / 2;
    const int NBINS = (N + BIN_NODES - 1) / BIN_NODES;
    // fixed per-bin edge capacity: 2x the mean (+45 sigma for Poisson bins)
    int ECAP = ((2 * (E / NBINS)) + 1023) & ~1023;
    if (ECAP < 2048) ECAP = 2048;

    const int* src = ei;
    const int* dst = ei + E;

    // workspace layout
    char* p = (char*)d_ws;
    auto alloc = [&](size_t bytes) -> void* {
        void* r = (void*)p;
        p += (bytes + 255) & ~(size_t)255;
        return r;
    };
    const size_t CSR_CAP = (size_t)E + 4 * (size_t)N + 64;
    float* dinvp    = (float*)alloc((size_t)N * 4);
    int*   row_start= (int*)alloc((size_t)N * 4);
    int*   row_len  = (int*)alloc((size_t)N * 4);
    int*   gcursor  = (int*)alloc((size_t)N * 4);
    int*   binbase  = (int*)alloc((size_t)NBINS * 4);
    int*   binpad   = (int*)alloc((size_t)NBINS * 4);
    int*   bincur   = (int*)alloc((size_t)NBINS * 4);      // | contiguous zero
    int*   gtotal   = (int*)alloc(4);                      //  | region
    float* pooled   = (float*)alloc((size_t)G * 64 * 4);   // |
    char*  zero_end = p;
    int*   ebuf     = (int*)alloc((size_t)NBINS * ECAP * 4);
    int*   csr      = (int*)alloc(CSR_CAP * 4);
    unsigned short* h_a = (unsigned short*)alloc((size_t)(N + 1) * 64 * 2); // +sentinel row
    unsigned short* h_b = (unsigned short*)alloc((size_t)N * 64 * 2);
    (void)ws_size;

    // ---- graph preprocessing (3 launches + 1 memset) ----
    hipMemsetAsync(bincur, 0, (size_t)(zero_end - (char*)bincur), stream);
    const int nchunks = (E + P1_CHUNK - 1) / P1_CHUNK;
    phase1_kernel<<<nchunks, P1_THREADS, 0, stream>>>(src, dst, bincur, ebuf, E, ECAP);
    bincount_kernel<<<NBINS, 1024, 0, stream>>>(ebuf, bincur, ECAP, dinvp,
                                                row_start, row_len, binbase,
                                                binpad, gtotal,
                                                h_a + (size_t)N * 64, N);
    phase2_kernel<<<NBINS, P2_THREADS, 0, stream>>>(ebuf, bincur, ECAP, row_start,
                                                    row_len, binbase, binpad,
                                                    csr, gcursor, N, N);

    const int nblk = (N + 3) / 4;
    const int lblk = (N + 63) / 64;
    // ---- layer 0 ----
    lin_mfma<128, false><<<lblk, 256, 0, stream>>>(x, w0, dinvp, h_a, N);
    agg_kernel<false><<<nblk, 256, 0, stream>>>(h_a, row_start, row_len, csr, dinvp,
                                                b0, g0, be0, m0, v0, h_b,
                                                batch, pooled, N);
    // ---- layer 1 ----
    lin_mfma<64, true><<<lblk, 256, 0, stream>>>(h_b, w1, dinvp, h_a, N);
    agg_kernel<false><<<nblk, 256, 0, stream>>>(h_a, row_start, row_len, csr, dinvp,
                                                b1, g1, be1, m1, v1, h_b,
                                                batch, pooled, N);
    // ---- layer 2 (pool fused) ----
    lin_mfma<64, true><<<lblk, 256, 0, stream>>>(h_b, w2, dinvp, h_a, N);
    agg_kernel<true><<<nblk, 256, 0, stream>>>(h_a, row_start, row_len, csr, dinvp,
                                               b2, g2, be2, m2, v2, h_b,
                                               batch, pooled, N);
    // ---- MLP ----
    mlp_kernel<<<G, 64, 0, stream>>>(pooled, l1w, l1b, l2w, l2b, out);
}

// Round 4
// 345.497 us; speedup vs baseline: 1.5126x; 1.5126x over previous
//
#include <hip/hip_runtime.h>
#include <hip/hip_bf16.h>

#define BN_EPS 1e-5f

typedef short bf16x8 __attribute__((ext_vector_type(8)));
typedef float f32x4 __attribute__((ext_vector_type(4)));

static __device__ __forceinline__ unsigned short f2bf(float f) {
    unsigned u = __float_as_uint(f);
    unsigned r = (u + 0x7FFF + ((u >> 16) & 1)) >> 16;
    return (unsigned short)r;
}
static __device__ __forceinline__ float bf2f(unsigned short s) {
    return __uint_as_float((unsigned)s << 16);
}
__device__ __forceinline__ int pad4i(int c) { return (c + 3) & ~3; }

#define BIN_SHIFT 9
#define BIN_NODES 512
#define P1_CHUNK 8192
#define P1_THREADS 1024
#define P1_PER_THREAD (P1_CHUNK / P1_THREADS)   // 8
#define IMG_CAP 12288
#define P2_THREADS 512

// ---------------- phase 1: partition edges into fixed-capacity 512-node bins
__global__ __launch_bounds__(P1_THREADS) void phase1_kernel(
        const int* __restrict__ src, const int* __restrict__ dst,
        int* __restrict__ bincur, int* __restrict__ ebuf, int e, int ecap) {
    __shared__ int hist[256], base[256], cur[256];
    int t = threadIdx.x;
    int c0 = blockIdx.x * P1_CHUNK;
    int iend = c0 + P1_CHUNK; if (iend > e) iend = e;
    if (t < 256) hist[t] = 0;
    __syncthreads();
    int dreg[P1_PER_THREAD];
#pragma unroll
    for (int u = 0; u < P1_PER_THREAD; u++) {
        int i = c0 + t + u * P1_THREADS;
        if (i < iend) {
            int d = dst[i];
            dreg[u] = d;
            atomicAdd(&hist[d >> BIN_SHIFT], 1);
        }
    }
    __syncthreads();
    if (t < 256) {
        if (hist[t] > 0)
            base[t] = t * ecap + atomicAdd(&bincur[t], hist[t]);
        cur[t] = 0;
    }
    __syncthreads();
#pragma unroll
    for (int u = 0; u < P1_PER_THREAD; u++) {
        int i = c0 + t + u * P1_THREADS;
        if (i < iend) {
            int s = src[i], d = dreg[u];
            int b = d >> BIN_SHIFT;
            int r = atomicAdd(&cur[b], 1);
            int p = base[b] + r;
            if (p < (b + 1) * ecap)                 // capacity guard (never in practice)
                ebuf[p] = s | ((d & (BIN_NODES - 1)) << 17);
        }
    }
}

// ---------------- per-node counts + dinv + row_start/row_len ---------------
// Bin CSR bases allocated via one global atomicAdd (bins need not be ordered),
// eliminating the separate scan kernel and its full-device drain.
// Also zeroes the sentinel row of h_a (fused). 1024 threads (16 waves).
__global__ __launch_bounds__(1024) void bincount_kernel(
        const int* __restrict__ ebuf, const int* __restrict__ bincur, int ecap,
        float* __restrict__ dinv, int* __restrict__ row_start,
        int* __restrict__ row_len, int* __restrict__ binbase,
        int* __restrict__ binpad, int* __restrict__ gtotal,
        unsigned short* __restrict__ ha_sent, int n) {
    __shared__ int c512[BIN_NODES];
    __shared__ int sd[256];
    __shared__ int rbs;
    int b = blockIdx.x, t = threadIdx.x;
    if (b == 0 && t < 64) ha_sent[t] = 0;           // zero sentinel row (fused)
    if (t < BIN_NODES) c512[t] = 0;
    __syncthreads();
    int cnt_b = bincur[b]; if (cnt_b > ecap) cnt_b = ecap;
    int e0 = b * ecap, e1 = e0 + cnt_b;
    for (int j = e0 + t; j < e1; j += 1024)
        atomicAdd(&c512[ebuf[j] >> 17], 1);
    __syncthreads();
    int n0 = b * BIN_NODES;
    // dinv (counts +1 for self-loop)
    if (t < BIN_NODES) {
        int i = n0 + t;
        if (i < n) dinv[i] = rsqrtf((float)(c512[t] + 1));
    }
    // exclusive prefix scan of pad4(count) over 512 nodes (2 per lead thread)
    int v0 = 0, v1 = 0, tsum = 0;
    if (t < 256) {
        v0 = pad4i(c512[2 * t]);
        v1 = pad4i(c512[2 * t + 1]);
        tsum = v0 + v1;
        sd[t] = tsum;
    }
    __syncthreads();
    for (int off = 1; off < 256; off <<= 1) {
        int x = 0;
        if (t < 256 && t >= off) x = sd[t - off];
        __syncthreads();
        if (t < 256) sd[t] += x;
        __syncthreads();
    }
    if (t == 0) {
        int tot = sd[255];
        int rb = atomicAdd(gtotal, tot);
        rbs = rb; binbase[b] = rb; binpad[b] = tot;
    }
    __syncthreads();
    if (t < 256) {
        int rb = rbs;
        int excl = sd[t] - tsum;
        int i0 = n0 + 2 * t, i1 = i0 + 1;
        if (i0 < n) { row_start[i0] = rb + excl;      row_len[i0] = v0; }
        if (i1 < n) { row_start[i1] = rb + excl + v0; row_len[i1] = v1; }
    }
}

// ---------------- phase 2: per-bin CSR build in LDS, coalesced write-out ----
__global__ __launch_bounds__(P2_THREADS) void phase2_kernel(
        const int* __restrict__ ebuf, const int* __restrict__ bincur, int ecap,
        const int* __restrict__ row_start, const int* __restrict__ row_len,
        const int* __restrict__ binbase, const int* __restrict__ binpad,
        int* __restrict__ csr, int* __restrict__ gcursor, int n, int sentinel) {
    __shared__ int image[IMG_CAP];
    __shared__ int lcur[BIN_NODES];
    __shared__ int rl[BIN_NODES];
    int b = blockIdx.x, t = threadIdx.x;
    int n0 = b * BIN_NODES;
    int nloc = n - n0; if (nloc > BIN_NODES) nloc = BIN_NODES;
    int rb = binbase[b];
    int rspan = binpad[b];
    int cnt_b = bincur[b]; if (cnt_b > ecap) cnt_b = ecap;
    int e0 = b * ecap, e1 = e0 + cnt_b;
    if (t < BIN_NODES) {
        rl[t] = (t < nloc) ? row_start[n0 + t] - rb : 0;
        lcur[t] = 0;
    }
    __syncthreads();
    if (rspan <= IMG_CAP) {
        for (int k = t; k < rspan; k += P2_THREADS) image[k] = sentinel;
        __syncthreads();
        for (int j = e0 + t; j < e1; j += P2_THREADS) {
            int en = ebuf[j];
            int s = en & 0x1FFFF;
            int dl = en >> 17;
            int pos = rl[dl] + atomicAdd(&lcur[dl], 1);
            image[pos] = s;
        }
        __syncthreads();
        for (int k = t; k < rspan; k += P2_THREADS) csr[rb + k] = image[k];
    } else {                                        // statistically never
        for (int k = t; k < nloc; k += P2_THREADS) gcursor[n0 + k] = 0;
        __syncthreads();
        for (int j = e0 + t; j < e1; j += P2_THREADS) {
            int en = ebuf[j];
            int s = en & 0x1FFFF;
            int dl = en >> 17;
            int pos = rb + rl[dl] + atomicAdd(&gcursor[n0 + dl], 1);
            csr[pos] = s;
        }
        __syncthreads();
        for (int k = t; k < nloc; k += P2_THREADS) { // fill pads with sentinel
            int node = n0 + k;
            int st = rb + rl[k] + gcursor[node];
            int en2 = rb + rl[k] + row_len[node];
            for (int pos = st; pos < en2; pos++) csr[pos] = sentinel;
        }
    }
}

// ---------------- MFMA linear: hs[N,64] = dinv[r] * (in[N,K] @ w[K,64]) ----
template<int K, bool BF16IN>
__global__ __launch_bounds__(256) void lin_mfma(const void* __restrict__ in_,
                                                const float* __restrict__ w,
                                                const float* __restrict__ dinv,
                                                unsigned short* __restrict__ outbf, int n) {
    constexpr int XS = K + 8;
    __shared__ unsigned short xs[64 * XS];
    __shared__ unsigned short wt[64 * XS];
    int t = threadIdx.x;
    int row0 = blockIdx.x * 64;
    int nrows = n - row0; if (nrows > 64) nrows = 64;

    {
        const float4* w4 = (const float4*)w;
        for (int idx = t; idx < K * 16; idx += 256) {
            int k = idx >> 4, c4 = (idx & 15) * 4;
            float4 v = w4[idx];
            wt[(c4 + 0) * XS + k] = f2bf(v.x);
            wt[(c4 + 1) * XS + k] = f2bf(v.y);
            wt[(c4 + 2) * XS + k] = f2bf(v.z);
            wt[(c4 + 3) * XS + k] = f2bf(v.w);
        }
    }
    if constexpr (BF16IN) {
        const uint4* in4 = (const uint4*)((const unsigned short*)in_ + (size_t)row0 * K);
        int total8 = nrows * (K / 8);
        for (int idx = t; idx < total8; idx += 256) {
            int r = idx / (K / 8), kk = idx - r * (K / 8);
            uint4 v = in4[idx];
            *(uint4*)&xs[r * XS + kk * 8] = v;
        }
    } else {
        const float4* in4 = (const float4*)((const float*)in_ + (size_t)row0 * K);
        int total4 = nrows * (K / 4);
        for (int idx = t; idx < total4; idx += 256) {
            int r = idx / (K / 4), kk = idx - r * (K / 4);
            float4 v = in4[idx];
            ushort4 s4;
            s4.x = f2bf(v.x); s4.y = f2bf(v.y); s4.z = f2bf(v.z); s4.w = f2bf(v.w);
            *(ushort4*)&xs[r * XS + kk * 4] = s4;
        }
    }
    __syncthreads();

    int lane = t & 63;
    int wid = t >> 6;
    int quad = lane >> 4;
    int l15 = lane & 15;

    f32x4 acc[4];
#pragma unroll
    for (int cg_ = 0; cg_ < 4; cg_++) acc[cg_] = (f32x4){0.f, 0.f, 0.f, 0.f};

    const unsigned short* xrow = &xs[(wid * 16 + l15) * XS + quad * 8];
#pragma unroll
    for (int kc = 0; kc < K / 32; kc++) {
        bf16x8 bfrag = *(const bf16x8*)(xrow + kc * 32);
#pragma unroll
        for (int cg_ = 0; cg_ < 4; cg_++) {
            bf16x8 afrag = *(const bf16x8*)&wt[(cg_ * 16 + l15) * XS + kc * 32 + quad * 8];
            acc[cg_] = __builtin_amdgcn_mfma_f32_16x16x32_bf16(afrag, bfrag, acc[cg_], 0, 0, 0);
        }
    }

    int grow = row0 + wid * 16 + l15;
    if (grow < n) {
        float dv = dinv[grow];
#pragma unroll
        for (int cg_ = 0; cg_ < 4; cg_++) {
            ushort4 st;
            st.x = f2bf(acc[cg_][0] * dv);
            st.y = f2bf(acc[cg_][1] * dv);
            st.z = f2bf(acc[cg_][2] * dv);
            st.w = f2bf(acc[cg_][3] * dv);
            *(ushort4*)&outbf[(size_t)grow * 64 + cg_ * 16 + quad * 4] = st;
        }
    }
}

// ---------------- aggregation + bias + BN + ReLU (uniform CSR walk) --------
// Rows are x4 padded (sentinel entries gather the zeroed sentinel row).
// i/rs/re/csr-entries scalarized via readfirstlane -> CSR reads go through
// the SMEM pipe; gathers are 64-lane broadcast row reads (2 B/lane, 128 B
// contiguous -> 2 cache lines per instruction). POOL fuses global_add_pool.
template<bool POOL>
__global__ __launch_bounds__(256) void agg_kernel(
        const unsigned short* __restrict__ hs, const int* __restrict__ row_start,
        const int* __restrict__ row_len, const int* __restrict__ csr,
        const float* __restrict__ dinv,
        const float* __restrict__ bias, const float* __restrict__ gam,
        const float* __restrict__ bet, const float* __restrict__ mu,
        const float* __restrict__ var,
        unsigned short* __restrict__ out,
        const int* __restrict__ batch, float* __restrict__ pooled, int n) {
    int iw = blockIdx.x * 4 + (threadIdx.x >> 6);
    unsigned lane = threadIdx.x & 63;
    if (iw >= n) return;                            // wave-uniform exit
    int i = __builtin_amdgcn_readfirstlane(iw);
    float acc = bf2f(hs[((unsigned)i << 6) + lane]); // self-loop (pre-scaled)
    int rs = __builtin_amdgcn_readfirstlane(row_start[i]);
    int re = rs + __builtin_amdgcn_readfirstlane(row_len[i]);   // x4 padded
    int j = rs;
    for (; j + 16 <= re; j += 16) {
        int s0 = __builtin_amdgcn_readfirstlane(csr[j + 0]);
        int s1 = __builtin_amdgcn_readfirstlane(csr[j + 1]);
        int s2 = __builtin_amdgcn_readfirstlane(csr[j + 2]);
        int s3 = __builtin_amdgcn_readfirstlane(csr[j + 3]);
        int s4 = __builtin_amdgcn_readfirstlane(csr[j + 4]);
        int s5 = __builtin_amdgcn_readfirstlane(csr[j + 5]);
        int s6 = __builtin_amdgcn_readfirstlane(csr[j + 6]);
        int s7 = __builtin_amdgcn_readfirstlane(csr[j + 7]);
        int s8 = __builtin_amdgcn_readfirstlane(csr[j + 8]);
        int s9 = __builtin_amdgcn_readfirstlane(csr[j + 9]);
        int sA = __builtin_amdgcn_readfirstlane(csr[j + 10]);
        int sB = __builtin_amdgcn_readfirstlane(csr[j + 11]);
        int sC = __builtin_amdgcn_readfirstlane(csr[j + 12]);
        int sD = __builtin_amdgcn_readfirstlane(csr[j + 13]);
        int sE = __builtin_amdgcn_readfirstlane(csr[j + 14]);
        int sF = __builtin_amdgcn_readfirstlane(csr[j + 15]);
        float h0 = bf2f(hs[((unsigned)s0 << 6) + lane]);
        float h1 = bf2f(hs[((unsigned)s1 << 6) + lane]);
        float h2 = bf2f(hs[((unsigned)s2 << 6) + lane]);
        float h3 = bf2f(hs[((unsigned)s3 << 6) + lane]);
        float h4 = bf2f(hs[((unsigned)s4 << 6) + lane]);
        float h5 = bf2f(hs[((unsigned)s5 << 6) + lane]);
        float h6 = bf2f(hs[((unsigned)s6 << 6) + lane]);
        float h7 = bf2f(hs[((unsigned)s7 << 6) + lane]);
        float h8 = bf2f(hs[((unsigned)s8 << 6) + lane]);
        float h9 = bf2f(hs[((unsigned)s9 << 6) + lane]);
        float hA = bf2f(hs[((unsigned)sA << 6) + lane]);
        float hB = bf2f(hs[((unsigned)sB << 6) + lane]);
        float hC = bf2f(hs[((unsigned)sC << 6) + lane]);
        float hD = bf2f(hs[((unsigned)sD << 6) + lane]);
        float hE = bf2f(hs[((unsigned)sE << 6) + lane]);
        float hF = bf2f(hs[((unsigned)sF << 6) + lane]);
        acc += (((h0 + h1) + (h2 + h3)) + ((h4 + h5) + (h6 + h7)))
             + (((h8 + h9) + (hA + hB)) + ((hC + hD) + (hE + hF)));
    }
    for (; j < re; j += 4) {
        int s0 = __builtin_amdgcn_readfirstlane(csr[j + 0]);
        int s1 = __builtin_amdgcn_readfirstlane(csr[j + 1]);
        int s2 = __builtin_amdgcn_readfirstlane(csr[j + 2]);
        int s3 = __builtin_amdgcn_readfirstlane(csr[j + 3]);
        float h0 = bf2f(hs[((unsigned)s0 << 6) + lane]);
        float h1 = bf2f(hs[((unsigned)s1 << 6) + lane]);
        float h2 = bf2f(hs[((unsigned)s2 << 6) + lane]);
        float h3 = bf2f(hs[((unsigned)s3 << 6) + lane]);
        acc += (h0 + h1) + (h2 + h3);
    }
    float agg = acc * dinv[i];
    float scale = gam[lane] * rsqrtf(var[lane] + BN_EPS);
    float r = (agg + bias[lane] - mu[lane]) * scale + bet[lane];
    unsigned short sv = f2bf(r > 0.f ? r : 0.f);
    out[((unsigned)i << 6) + lane] = sv;
    if (POOL) {
        int g = __builtin_amdgcn_readfirstlane(batch[i]);
        atomicAdd(&pooled[(size_t)g * 64 + lane], bf2f(sv));
    }
}

// ---------------- pool stage 2: tiny MLP per graph ----------------
__global__ void mlp_kernel(const float* __restrict__ pooled,
                           const float* __restrict__ l1w, const float* __restrict__ l1b,
                           const float* __restrict__ l2w, const float* __restrict__ l2b,
                           float* __restrict__ out) {
    int g = blockIdx.x;
    int lane = threadIdx.x;
    __shared__ float p[64];
    __shared__ float h1[32];
    p[lane] = pooled[(size_t)g * 64 + lane];
    __syncthreads();
    if (lane < 32) {
        float a = l1b[lane];
#pragma unroll 8
        for (int k = 0; k < 64; k++) a += p[k] * l1w[k * 32 + lane];
        h1[lane] = a > 0.f ? a : 0.f;
    }
    __syncthreads();
    if (lane < 2) {
        float a = l2b[lane];
#pragma unroll 8
        for (int j = 0; j < 32; j++) a += h1[j] * l2w[j * 2 + lane];
        out[g * 2 + lane] = a;
    }
}

extern "C" void kernel_launch(void* const* d_in, const int* in_sizes, int n_in,
                              void* d_out, int out_size, void* d_ws, size_t ws_size,
                              hipStream_t stream) {
    const float* x     = (const float*)d_in[0];
    const int*   ei    = (const int*)d_in[1];
    const int*   batch = (const int*)d_in[2];
    const float* w0 = (const float*)d_in[3];
    const float* b0 = (const float*)d_in[4];
    const float* w1 = (const float*)d_in[5];
    const float* b1 = (const float*)d_in[6];
    const float* w2 = (const float*)d_in[7];
    const float* b2 = (const float*)d_in[8];
    const float* g0 = (const float*)d_in[9];
    const float* be0 = (const float*)d_in[10];
    const float* m0 = (const float*)d_in[11];
    const float* v0 = (const float*)d_in[12];
    const float* g1 = (const float*)d_in[13];
    const float* be1 = (const float*)d_in[14];
    const float* m1 = (const float*)d_in[15];
    const float* v1 = (const float*)d_in[16];
    const float* g2 = (const float*)d_in[17];
    const float* be2 = (const float*)d_in[18];
    const float* m2 = (const float*)d_in[19];
    const float* v2 = (const float*)d_in[20];
    const float* l1w = (const float*)d_in[21];
    const float* l1b = (const float*)d_in[22];
    const float* l2w = (const float*)d_in[23];
    const float* l2b = (const float*)d_in[24];
    float* out = (float*)d_out;

    const int N = in_sizes[2];
    const int E = in_sizes[1] / 2;
    const int G = out_size / 2;
    const int NBINS = (N + BIN_NODES - 1) / BIN_NODES;
    // fixed per-bin edge capacity: 2x the mean (+45 sigma for Poisson bins)
    int ECAP = ((2 * (E / NBINS)) + 1023) & ~1023;
    if (ECAP < 2048) ECAP = 2048;

    const int* src = ei;
    const int* dst = ei + E;

    // workspace layout
    char* p = (char*)d_ws;
    auto alloc = [&](size_t bytes) -> void* {
        void* r = (void*)p;
        p += (bytes + 255) & ~(size_t)255;
        return r;
    };
    const size_t CSR_CAP = (size_t)E + 4 * (size_t)N + 64;
    float* dinvp    = (float*)alloc((size_t)N * 4);
    int*   row_start= (int*)alloc((size_t)N * 4);
    int*   row_len  = (int*)alloc((size_t)N * 4);
    int*   gcursor  = (int*)alloc((size_t)N * 4);
    int*   binbase  = (int*)alloc((size_t)NBINS * 4);
    int*   binpad   = (int*)alloc((size_t)NBINS * 4);
    int*   bincur   = (int*)alloc((size_t)NBINS * 4);      // | contiguous zero
    int*   gtotal   = (int*)alloc(4);                      //  | region
    float* pooled   = (float*)alloc((size_t)G * 64 * 4);   // |
    char*  zero_end = p;
    int*   ebuf     = (int*)alloc((size_t)NBINS * ECAP * 4);
    int*   csr      = (int*)alloc(CSR_CAP * 4);
    unsigned short* h_a = (unsigned short*)alloc((size_t)(N + 1) * 64 * 2); // +sentinel row
    unsigned short* h_b = (unsigned short*)alloc((size_t)N * 64 * 2);
    (void)ws_size;

    // ---- graph preprocessing (3 launches + 1 memset) ----
    hipMemsetAsync(bincur, 0, (size_t)(zero_end - (char*)bincur), stream);
    const int nchunks = (E + P1_CHUNK - 1) / P1_CHUNK;
    phase1_kernel<<<nchunks, P1_THREADS, 0, stream>>>(src, dst, bincur, ebuf, E, ECAP);
    bincount_kernel<<<NBINS, 1024, 0, stream>>>(ebuf, bincur, ECAP, dinvp,
                                                row_start, row_len, binbase,
                                                binpad, gtotal,
                                                h_a + (size_t)N * 64, N);
    phase2_kernel<<<NBINS, P2_THREADS, 0, stream>>>(ebuf, bincur, ECAP, row_start,
                                                    row_len, binbase, binpad,
                                                    csr, gcursor, N, N);

    const int nblk = (N + 3) / 4;
    const int lblk = (N + 63) / 64;
    // ---- layer 0 ----
    lin_mfma<128, false><<<lblk, 256, 0, stream>>>(x, w0, dinvp, h_a, N);
    agg_kernel<false><<<nblk, 256, 0, stream>>>(h_a, row_start, row_len, csr, dinvp,
                                                b0, g0, be0, m0, v0, h_b,
                                                batch, pooled, N);
    // ---- layer 1 ----
    lin_mfma<64, true><<<lblk, 256, 0, stream>>>(h_b, w1, dinvp, h_a, N);
    agg_kernel<false><<<nblk, 256, 0, stream>>>(h_a, row_start, row_len, csr, dinvp,
                                                b1, g1, be1, m1, v1, h_b,
                                                batch, pooled, N);
    // ---- layer 2 (pool fused) ----
    lin_mfma<64, true><<<lblk, 256, 0, stream>>>(h_b, w2, dinvp, h_a, N);
    agg_kernel<true><<<nblk, 256, 0, stream>>>(h_a, row_start, row_len, csr, dinvp,
                                               b2, g2, be2, m2, v2, h_b,
                                               batch, pooled, N);
    // ---- MLP ----
    mlp_kernel<<<G, 64, 0, stream>>>(pooled, l1w, l1b, l2w, l2b, out);
}